// Round 5
// baseline (586.109 us; speedup 1.0000x reference)
//
#include <hip/hip_runtime.h>
#include <stdint.h>

#define M_TOK 4096
#define K_IN  4096
#define N_OUT 11008
#define GROUPS 64
#define WPR 512            // packed words per weight row = K_IN/8

// ---- 256x256 8-phase GEMM geometry ----
#define BM 256
#define BN 256
#define BK 64
#define TM (M_TOK / BM)    // 16
#define TN (N_OUT / BN)    // 43
#define NWG (TM * TN)      // 688  (688 % 8 == 0 -> simple bijective XCD swizzle)
#define KTILES (K_IN / BK) // 64

typedef __bf16 bf16x8 __attribute__((ext_vector_type(8)));
typedef float  f32x4  __attribute__((ext_vector_type(4)));

__device__ __forceinline__ uint16_t f2bf(float f) {
  uint32_t u = __float_as_uint(f);
  u += 0x7FFFu + ((u >> 16) & 1u);
  return (uint16_t)(u >> 16);
}

// ---------------------------------------------------------------------------
// Fused preprocessing, round 5: W-branch vectorized per G13.
//  X-branch (blocks [0, XBLK)): x fp32->bf16, 32 B/lane loads (unchanged).
//  W-branch: each thread loads ONE uint4 of qw (16 B/lane, 4 consecutive
//  words = 32 weights, all within one quant group -> single zw/sc fetch)
//  and stores 64 B of contiguous bf16 (4x dwordx4). Previous rounds used
//  4 B scalar qw loads (G13 violation, ~2-2.5x slow for a streaming op).
//  Dequant math unchanged (same f2bf / fmaf) -> bit-identical output.
// ---------------------------------------------------------------------------
#define XBLK ((M_TOK * K_IN) / (256 * 8))        // 8192
#define WBLK ((N_OUT * WPR) / (256 * 4))         // 5504

__global__ __launch_bounds__(256) void prep(const float* __restrict__ x,
                                            const uint32_t* __restrict__ qw,
                                            const uint32_t* __restrict__ qz,
                                            const float* __restrict__ sc,
                                            uint16_t* __restrict__ xb,
                                            uint16_t* __restrict__ wb) {
  if (blockIdx.x < XBLK) {
    size_t i = ((size_t)blockIdx.x * 256 + threadIdx.x) * 8;
    const float4* p = (const float4*)(x + i);
    float4 a = p[0];
    float4 b = p[1];
    uint4 v;
    v.x = (uint32_t)f2bf(a.x) | ((uint32_t)f2bf(a.y) << 16);
    v.y = (uint32_t)f2bf(a.z) | ((uint32_t)f2bf(a.w) << 16);
    v.z = (uint32_t)f2bf(b.x) | ((uint32_t)f2bf(b.y) << 16);
    v.w = (uint32_t)f2bf(b.z) | ((uint32_t)f2bf(b.w) << 16);
    *(uint4*)(xb + i) = v;
  } else {
    // t = uint4 index into qw. Row o = t>>7 (128 uint4 per 512-word row),
    // words 4t..4t+3 share group g = (t&127)>>1.
    int t = (blockIdx.x - XBLK) * 256 + threadIdx.x;
    int o  = t >> 7;
    int g  = (t & 127) >> 1;
    uint32_t zw = qz[o * (GROUPS / 8) + (g >> 3)];
    float zp = (float)((zw >> ((g & 7) * 4)) & 15u);
    float s = sc[o * GROUPS + g];
    float c = -s * zp;
    uint4 w4 = ((const uint4*)qw)[t];
    uint4* out = (uint4*)wb + (size_t)t * 4;
    uint32_t ws[4] = {w4.x, w4.y, w4.z, w4.w};
#pragma unroll
    for (int q = 0; q < 4; q++) {
      uint32_t w = ws[q];
      uint4 v;
      uint32_t r[4];
#pragma unroll
      for (int j = 0; j < 4; j++) {
        float f0 = (float)((w >> (8 * j)) & 15u);
        float f1 = (float)((w >> (8 * j + 4)) & 15u);
        r[j] = (uint32_t)f2bf(fmaf(f0, s, c)) | ((uint32_t)f2bf(fmaf(f1, s, c)) << 16);
      }
      v.x = r[0]; v.y = r[1]; v.z = r[2]; v.w = r[3];
      out[q] = v;
    }
  }
}

// ---------------------------------------------------------------------------
// 256x256x64 8-phase bf16 GEMM — byte-identical to round 4 (941 TF, 41%
// MfmaUtil, 0 bank conflicts, FETCH at compulsory minimum). Round-4 A/B
// established the compiler re-inserts lgkmcnt(0) at barriers, so rounds 3/4
// compile equivalently; this structure is left untouched while the prep gap
// is isolated.
// ---------------------------------------------------------------------------
#define SBAR()   __builtin_amdgcn_s_barrier()
#define SCHED0() __builtin_amdgcn_sched_barrier(0)
#define WAITV(n) asm volatile("s_waitcnt vmcnt(" #n ")" ::: "memory")

#define STAGE_A(buf, half, kt) do {                                            \
  _Pragma("unroll")                                                            \
  for (int c_ = 0; c_ < 2; c_++) {                                             \
    const int r_ = (half) * 128 + c_ * 64 + wave * 8;                          \
    __builtin_amdgcn_global_load_lds(                                          \
        (const __attribute__((address_space(1))) uint32_t*)(                   \
            gA + (size_t)r_ * K_IN + (size_t)(kt) * BK),                       \
        (__attribute__((address_space(3))) uint32_t*)(&As[(buf)][r_][0]),      \
        16, 0, 0);                                                             \
  } } while (0)

#define STAGE_B(buf, half, kt) do {                                            \
  _Pragma("unroll")                                                            \
  for (int c_ = 0; c_ < 2; c_++) {                                             \
    const int r_ = (half) * 128 + c_ * 64 + wave * 8;                          \
    __builtin_amdgcn_global_load_lds(                                          \
        (const __attribute__((address_space(1))) uint32_t*)(                   \
            gB + (size_t)r_ * K_IN + (size_t)(kt) * BK),                       \
        (__attribute__((address_space(3))) uint32_t*)(&Bs[(buf)][r_][0]),      \
        16, 0, 0);                                                             \
  } } while (0)

#define LOAD_A(buf, mh) do {                                                   \
  _Pragma("unroll")                                                            \
  for (int i2_ = 0; i2_ < 4; i2_++) {                                          \
    const int row_ = (mh) * 128 + wm * 64 + i2_ * 16 + col;                    \
    af[i2_][0] = *(const bf16x8*)&As[(buf)][row_][(quad ^ cs) << 3];           \
    af[i2_][1] = *(const bf16x8*)&As[(buf)][row_][((4 + quad) ^ cs) << 3];     \
  } } while (0)

#define LOAD_B(buf, nh) do {                                                   \
  _Pragma("unroll")                                                            \
  for (int j2_ = 0; j2_ < 2; j2_++) {                                          \
    const int row_ = (nh) * 128 + wn * 32 + j2_ * 16 + col;                    \
    bfr[j2_][0] = *(const bf16x8*)&Bs[(buf)][row_][(quad ^ cs) << 3];          \
    bfr[j2_][1] = *(const bf16x8*)&Bs[(buf)][row_][((4 + quad) ^ cs) << 3];    \
  } } while (0)

#define MMA(mh, nh) do {                                                       \
  __builtin_amdgcn_s_setprio(1);                                               \
  _Pragma("unroll")                                                            \
  for (int i2_ = 0; i2_ < 4; i2_++)                                            \
    _Pragma("unroll")                                                          \
    for (int j2_ = 0; j2_ < 2; j2_++) {                                        \
      acc[(mh)*4 + i2_][(nh)*2 + j2_] = __builtin_amdgcn_mfma_f32_16x16x32_bf16( \
          af[i2_][0], bfr[j2_][0], acc[(mh)*4 + i2_][(nh)*2 + j2_], 0, 0, 0);  \
      acc[(mh)*4 + i2_][(nh)*2 + j2_] = __builtin_amdgcn_mfma_f32_16x16x32_bf16( \
          af[i2_][1], bfr[j2_][1], acc[(mh)*4 + i2_][(nh)*2 + j2_], 0, 0, 0);  \
    }                                                                          \
  __builtin_amdgcn_s_setprio(0); } while (0)

__global__ __launch_bounds__(512, 2) void gemm_bf16(const uint16_t* __restrict__ A,
                                                    const uint16_t* __restrict__ B,
                                                    const float* __restrict__ bias,
                                                    float* __restrict__ C) {
  __shared__ __align__(16) uint16_t As[2][BM][BK];   // 64 KiB
  __shared__ __align__(16) uint16_t Bs[2][BN][BK];   // 64 KiB

  const int bid = blockIdx.x;
  const int wg  = (bid & 7) * (NWG / 8) + (bid >> 3);
  const int mt  = wg / TN;
  const int nt  = wg % TN;
  const size_t m0 = (size_t)mt * BM;
  const size_t n0 = (size_t)nt * BN;

  const int tid  = threadIdx.x;
  const int wave = tid >> 6;
  const int lane = tid & 63;
  const int wm   = wave >> 2;          // 0..1
  const int wn   = wave & 3;           // 0..3
  const int lrow = lane >> 3;          // 0..7
  const int lcol = lane & 7;           // 0..7
  const int col  = lane & 15;
  const int quad = lane >> 4;
  const int cs   = col & 7;

  const uint16_t* gA = A + (m0 + lrow) * K_IN + (size_t)((lcol ^ lrow) << 3);
  const uint16_t* gB = B + (n0 + lrow) * K_IN + (size_t)((lcol ^ lrow) << 3);

  f32x4 acc[8][4];
#pragma unroll
  for (int i = 0; i < 8; i++)
#pragma unroll
    for (int j = 0; j < 4; j++)
      acc[i][j] = (f32x4){0.f, 0.f, 0.f, 0.f};

  bf16x8 af[4][2];
  bf16x8 bfr[2][2];

  STAGE_A(0, 0, 0); STAGE_B(0, 1, 0); STAGE_B(0, 0, 0); STAGE_A(0, 1, 0);
  STAGE_A(1, 0, 1); STAGE_B(1, 1, 1);
  WAITV(6);
  SBAR(); SCHED0();

  for (int it = 0; it < KTILES / 2 - 1; ++it) {
    const int kt = 2 * it;
    LOAD_A(0, 0); LOAD_B(0, 0);
    STAGE_B(1, 0, kt + 1);
    SBAR();
    MMA(0, 0);
    SBAR(); SCHED0();
    LOAD_B(0, 1);
    STAGE_A(1, 1, kt + 1);
    SBAR();
    MMA(0, 1);
    WAITV(8);
    SBAR(); SCHED0();
    LOAD_A(0, 1);
    STAGE_A(0, 0, kt + 2);
    SBAR();
    MMA(1, 1);
    SBAR(); SCHED0();
    LOAD_B(0, 0);
    STAGE_B(0, 1, kt + 2);
    SBAR();
    MMA(1, 0);
    WAITV(6);
    SBAR(); SCHED0();
    LOAD_A(1, 0); LOAD_B(1, 0);
    STAGE_B(0, 0, kt + 2);
    SBAR();
    MMA(0, 0);
    SBAR(); SCHED0();
    LOAD_B(1, 1);
    STAGE_A(0, 1, kt + 2);
    SBAR();
    MMA(0, 1);
    WAITV(8);
    SBAR(); SCHED0();
    LOAD_A(1, 1);
    STAGE_A(1, 0, kt + 3);
    SBAR();
    MMA(1, 1);
    SBAR(); SCHED0();
    LOAD_B(1, 0);
    STAGE_B(1, 1, kt + 3);
    SBAR();
    MMA(1, 0);
    WAITV(6);
    SBAR(); SCHED0();
  }

  LOAD_A(0, 0); LOAD_B(0, 0);
  STAGE_B(1, 0, KTILES - 1);
  SBAR();
  MMA(0, 0);
  SBAR(); SCHED0();
  LOAD_B(0, 1);
  STAGE_A(1, 1, KTILES - 1);
  SBAR();
  MMA(0, 1);
  WAITV(8);
  SBAR(); SCHED0();
  LOAD_A(0, 1);
  SBAR();
  MMA(1, 1);
  SBAR(); SCHED0();
  LOAD_B(0, 0);
  SBAR();
  MMA(1, 0);
  WAITV(2);
  SBAR(); SCHED0();
  LOAD_A(1, 0); LOAD_B(1, 0);
  SBAR();
  MMA(0, 0);
  SBAR(); SCHED0();
  LOAD_B(1, 1);
  SBAR();
  MMA(0, 1);
  WAITV(0);
  SBAR(); SCHED0();
  LOAD_A(1, 1);
  SBAR();
  MMA(1, 1);
  SBAR(); SCHED0();
  LOAD_B(1, 0);
  SBAR();
  MMA(1, 0);

#pragma unroll
  for (int i = 0; i < 8; i++) {
    const int mrow = (int)m0 + (i >> 2) * 128 + wm * 64 + (i & 3) * 16 + quad * 4;
#pragma unroll
    for (int j = 0; j < 4; j++) {
      const int ncol = (int)n0 + (j >> 1) * 128 + wn * 32 + (j & 1) * 16 + col;
      const float bv = bias[ncol];
      float* out = C + (size_t)mrow * N_OUT + ncol;
#pragma unroll
      for (int r = 0; r < 4; r++)
        __builtin_nontemporal_store(acc[i][j][r] + bv, out + (size_t)r * N_OUT);
    }
  }
}

// ---------------------------------------------------------------------------
// Fallback (ws too small): correct but slow fused kernel.
// ---------------------------------------------------------------------------
__global__ __launch_bounds__(256) void fallback_fused(const float* __restrict__ x,
                                                      const uint32_t* __restrict__ qw,
                                                      const uint32_t* __restrict__ qz,
                                                      const float* __restrict__ sc,
                                                      const float* __restrict__ bias,
                                                      float* __restrict__ out) {
  __shared__ float xs[K_IN];
  const int t = blockIdx.y;
  const int o = blockIdx.x * 256 + threadIdx.x;
  for (int i = threadIdx.x; i < K_IN; i += 256) xs[i] = x[(size_t)t * K_IN + i];
  __syncthreads();
  float acc = 0.f;
  const uint32_t* qwr = qw + (size_t)o * WPR;
  for (int g = 0; g < GROUPS; g++) {
    uint32_t zw = qz[o * (GROUPS / 8) + (g >> 3)];
    float zp = (float)((zw >> ((g & 7) * 4)) & 15u);
    float s = sc[o * GROUPS + g];
    float gacc = 0.f, gsum = 0.f;
    for (int w = 0; w < 8; w++) {
      uint32_t wv = qwr[g * 8 + w];
#pragma unroll
      for (int j = 0; j < 8; j++) {
        float xv = xs[g * 64 + w * 8 + j];
        gacc = fmaf((float)((wv >> (4 * j)) & 15u), xv, gacc);
        gsum += xv;
      }
    }
    acc += s * (gacc - zp * gsum);
  }
  out[(size_t)t * N_OUT + o] = acc + bias[o];
}

// ---------------------------------------------------------------------------
extern "C" void kernel_launch(void* const* d_in, const int* in_sizes, int n_in,
                              void* d_out, int out_size, void* d_ws, size_t ws_size,
                              hipStream_t stream) {
  (void)in_sizes; (void)n_in; (void)out_size;
  const float*    x    = (const float*)d_in[0];
  const uint32_t* qw   = (const uint32_t*)d_in[1];
  const uint32_t* qz   = (const uint32_t*)d_in[2];
  const float*    sc   = (const float*)d_in[3];
  const float*    bias = (const float*)d_in[4];
  float* out = (float*)d_out;

  const size_t xb_bytes = (size_t)M_TOK * K_IN * 2;
  const size_t wb_bytes = (size_t)N_OUT * K_IN * 2;

  if (ws_size >= xb_bytes + wb_bytes) {
    uint16_t* xb = (uint16_t*)d_ws;
    uint16_t* wb = (uint16_t*)((char*)d_ws + xb_bytes);
    prep<<<XBLK + WBLK, 256, 0, stream>>>(x, qw, qz, sc, xb, wb);
    gemm_bf16<<<NWG, 512, 0, stream>>>(xb, wb, bias, out);
  } else {
    fallback_fused<<<dim3(N_OUT / 256, M_TOK), 256, 0, stream>>>(x, qw, qz, sc, bias, out);
  }
}

// Round 6
// 584.057 us; speedup vs baseline: 1.0035x; 1.0035x over previous
//
#include <hip/hip_runtime.h>
#include <stdint.h>

#define M_TOK 4096
#define K_IN  4096
#define N_OUT 11008
#define GROUPS 64
#define WPR 512            // packed words per weight row = K_IN/8

// ---- 256x256 8-phase GEMM geometry ----
#define BM 256
#define BN 256
#define BK 64
#define TM (M_TOK / BM)    // 16
#define TN (N_OUT / BN)    // 43
#define NWG (TM * TN)      // 688  (688 % 8 == 0 -> simple bijective XCD swizzle)
#define KTILES (K_IN / BK) // 64

typedef __bf16 bf16x8 __attribute__((ext_vector_type(8)));
typedef float  f32x4  __attribute__((ext_vector_type(4)));

__device__ __forceinline__ uint16_t f2bf(float f) {
  uint32_t u = __float_as_uint(f);
  u += 0x7FFFu + ((u >> 16) & 1u);
  return (uint16_t)(u >> 16);
}

// ---------------------------------------------------------------------------
// Fused preprocessing (r5 form: uint4 W loads; three variants all measured
// equal, kept for its coalescing).
// ---------------------------------------------------------------------------
#define XBLK ((M_TOK * K_IN) / (256 * 8))        // 8192
#define WBLK ((N_OUT * WPR) / (256 * 4))         // 5504

__global__ __launch_bounds__(256) void prep(const float* __restrict__ x,
                                            const uint32_t* __restrict__ qw,
                                            const uint32_t* __restrict__ qz,
                                            const float* __restrict__ sc,
                                            uint16_t* __restrict__ xb,
                                            uint16_t* __restrict__ wb) {
  if (blockIdx.x < XBLK) {
    size_t i = ((size_t)blockIdx.x * 256 + threadIdx.x) * 8;
    const float4* p = (const float4*)(x + i);
    float4 a = p[0];
    float4 b = p[1];
    uint4 v;
    v.x = (uint32_t)f2bf(a.x) | ((uint32_t)f2bf(a.y) << 16);
    v.y = (uint32_t)f2bf(a.z) | ((uint32_t)f2bf(a.w) << 16);
    v.z = (uint32_t)f2bf(b.x) | ((uint32_t)f2bf(b.y) << 16);
    v.w = (uint32_t)f2bf(b.z) | ((uint32_t)f2bf(b.w) << 16);
    *(uint4*)(xb + i) = v;
  } else {
    int t = (blockIdx.x - XBLK) * 256 + threadIdx.x;
    int o  = t >> 7;
    int g  = (t & 127) >> 1;
    uint32_t zw = qz[o * (GROUPS / 8) + (g >> 3)];
    float zp = (float)((zw >> ((g & 7) * 4)) & 15u);
    float s = sc[o * GROUPS + g];
    float c = -s * zp;
    uint4 w4 = ((const uint4*)qw)[t];
    uint4* out = (uint4*)wb + (size_t)t * 4;
    uint32_t ws[4] = {w4.x, w4.y, w4.z, w4.w};
#pragma unroll
    for (int q = 0; q < 4; q++) {
      uint32_t w = ws[q];
      uint4 v;
      uint32_t r[4];
#pragma unroll
      for (int j = 0; j < 4; j++) {
        float f0 = (float)((w >> (8 * j)) & 15u);
        float f1 = (float)((w >> (8 * j + 4)) & 15u);
        r[j] = (uint32_t)f2bf(fmaf(f0, s, c)) | ((uint32_t)f2bf(fmaf(f1, s, c)) << 16);
      }
      v.x = r[0]; v.y = r[1]; v.z = r[2]; v.w = r[3];
      out[q] = v;
    }
  }
}

// ---------------------------------------------------------------------------
// 256x256x64 GEMM, round 6: overlap ds_read with MFMA.
//
// r3-r5 diagnosis: phase = {ds_reads | SBAR | MFMA | SBAR} serialized the
// CU-wide LDS drain (~770 cyc) against the MFMA cluster (~620 cyc) because
// reads and MFMAs sat on opposite sides of a barrier -> phase ~1360 cyc,
// MfmaUtil 41%. Fix: ONE barrier per phase at the END; frag LOADs move to
// the MFMA side. Loads + MFMAs are plain IR in one scheduling region, so
// the compiler emits progressive counted lgkmcnt: first MFMA waits only
// its own frags, remaining reads drain under the MFMA cluster.
//
// Ledger (UNCHANGED from r3/r5, HW-validated): reads stay phase-local.
//   stages: ph0 b1.Bh0<-kt+1, ph1 b1.Ah1<-kt+1, ph2 b0.Ah0<-kt+2,
//           ph3 b0.Bh1<-kt+2, ph4 b0.Bh0<-kt+2, ph5 b0.Ah1<-kt+2,
//           ph6 b1.Ah0<-kt+3, ph7 b1.Bh1<-kt+3   (2 loads/thread each)
//   waits:  vmcnt(8)@ph1-end, vmcnt(6)@ph3-end, vmcnt(8)@ph5-end,
//           vmcnt(6)@ph7-end  (>=6 loads in flight; 3-5 phase budget)
// Overwrite audit (end-of-phase barriers only): every stage target's last
// reader completes (lgkm-waited before its MMA) before that phase's closing
// barrier; stage issues >=1 phase later. Tightest: b0.Bh0 read ph2 ->
// barrier end-ph3 -> staged ph4. Safe.
// LDS swizzle: LDS[row][c] = global chunk (c ^ (row&7)) via pre-swizzled
// global source (global_load_lds dest stays linear); reads use kc^(row&7).
// ---------------------------------------------------------------------------
#define SBAR()   __builtin_amdgcn_s_barrier()
#define WAITV(n) asm volatile("s_waitcnt vmcnt(" #n ")" ::: "memory")

#define STAGE_A(buf, half, kt) do {                                            \
  _Pragma("unroll")                                                            \
  for (int c_ = 0; c_ < 2; c_++) {                                             \
    const int r_ = (half) * 128 + c_ * 64 + wave * 8;                          \
    __builtin_amdgcn_global_load_lds(                                          \
        (const __attribute__((address_space(1))) uint32_t*)(                   \
            gA + (size_t)r_ * K_IN + (size_t)(kt) * BK),                       \
        (__attribute__((address_space(3))) uint32_t*)(&As[(buf)][r_][0]),      \
        16, 0, 0);                                                             \
  } } while (0)

#define STAGE_B(buf, half, kt) do {                                            \
  _Pragma("unroll")                                                            \
  for (int c_ = 0; c_ < 2; c_++) {                                             \
    const int r_ = (half) * 128 + c_ * 64 + wave * 8;                          \
    __builtin_amdgcn_global_load_lds(                                          \
        (const __attribute__((address_space(1))) uint32_t*)(                   \
            gB + (size_t)r_ * K_IN + (size_t)(kt) * BK),                       \
        (__attribute__((address_space(3))) uint32_t*)(&Bs[(buf)][r_][0]),      \
        16, 0, 0);                                                             \
  } } while (0)

#define LOAD_A(buf, mh) do {                                                   \
  _Pragma("unroll")                                                            \
  for (int i2_ = 0; i2_ < 4; i2_++) {                                          \
    const int row_ = (mh) * 128 + wm * 64 + i2_ * 16 + col;                    \
    af[i2_][0] = *(const bf16x8*)&As[(buf)][row_][(quad ^ cs) << 3];           \
    af[i2_][1] = *(const bf16x8*)&As[(buf)][row_][((4 + quad) ^ cs) << 3];     \
  } } while (0)

#define LOAD_B(buf, nh) do {                                                   \
  _Pragma("unroll")                                                            \
  for (int j2_ = 0; j2_ < 2; j2_++) {                                          \
    const int row_ = (nh) * 128 + wn * 32 + j2_ * 16 + col;                    \
    bfr[j2_][0] = *(const bf16x8*)&Bs[(buf)][row_][(quad ^ cs) << 3];          \
    bfr[j2_][1] = *(const bf16x8*)&Bs[(buf)][row_][((4 + quad) ^ cs) << 3];    \
  } } while (0)

#define MMA(mh, nh) do {                                                       \
  __builtin_amdgcn_s_setprio(1);                                               \
  _Pragma("unroll")                                                            \
  for (int i2_ = 0; i2_ < 4; i2_++)                                            \
    _Pragma("unroll")                                                          \
    for (int j2_ = 0; j2_ < 2; j2_++) {                                        \
      acc[(mh)*4 + i2_][(nh)*2 + j2_] = __builtin_amdgcn_mfma_f32_16x16x32_bf16( \
          af[i2_][0], bfr[j2_][0], acc[(mh)*4 + i2_][(nh)*2 + j2_], 0, 0, 0);  \
      acc[(mh)*4 + i2_][(nh)*2 + j2_] = __builtin_amdgcn_mfma_f32_16x16x32_bf16( \
          af[i2_][1], bfr[j2_][1], acc[(mh)*4 + i2_][(nh)*2 + j2_], 0, 0, 0);  \
    }                                                                          \
  __builtin_amdgcn_s_setprio(0); } while (0)

__global__ __launch_bounds__(512, 2) void gemm_bf16(const uint16_t* __restrict__ A,
                                                    const uint16_t* __restrict__ B,
                                                    const float* __restrict__ bias,
                                                    float* __restrict__ C) {
  __shared__ __align__(16) uint16_t As[2][BM][BK];   // 64 KiB
  __shared__ __align__(16) uint16_t Bs[2][BN][BK];   // 64 KiB

  const int bid = blockIdx.x;
  const int wg  = (bid & 7) * (NWG / 8) + (bid >> 3);
  const int mt  = wg / TN;
  const int nt  = wg % TN;
  const size_t m0 = (size_t)mt * BM;
  const size_t n0 = (size_t)nt * BN;

  const int tid  = threadIdx.x;
  const int wave = tid >> 6;
  const int lane = tid & 63;
  const int wm   = wave >> 2;          // 0..1
  const int wn   = wave & 3;           // 0..3
  const int lrow = lane >> 3;          // 0..7
  const int lcol = lane & 7;           // 0..7
  const int col  = lane & 15;
  const int quad = lane >> 4;
  const int cs   = col & 7;

  const uint16_t* gA = A + (m0 + lrow) * K_IN + (size_t)((lcol ^ lrow) << 3);
  const uint16_t* gB = B + (n0 + lrow) * K_IN + (size_t)((lcol ^ lrow) << 3);

  f32x4 acc[8][4];
#pragma unroll
  for (int i = 0; i < 8; i++)
#pragma unroll
    for (int j = 0; j < 4; j++)
      acc[i][j] = (f32x4){0.f, 0.f, 0.f, 0.f};

  bf16x8 af[4][2];
  bf16x8 bfr[2][2];

  // prologue: buf0 <- kt0, buf1.{Ah0,Bh1} <- kt1; keep 3 halves in flight.
  STAGE_A(0, 0, 0); STAGE_B(0, 1, 0); STAGE_B(0, 0, 0); STAGE_A(0, 1, 0);
  STAGE_A(1, 0, 1); STAGE_B(1, 1, 1);
  WAITV(6);
  SBAR();

  for (int it = 0; it < KTILES / 2 - 1; ++it) {
    const int kt = 2 * it;
    // ph0: buf0 M0N0 ; stage b1.Bh0<-kt+1
    STAGE_B(1, 0, kt + 1);
    LOAD_A(0, 0); LOAD_B(0, 0);
    MMA(0, 0);
    SBAR();
    // ph1: M0N1 ; stage b1.Ah1<-kt+1 ; vmcnt(8)
    STAGE_A(1, 1, kt + 1);
    LOAD_B(0, 1);
    MMA(0, 1);
    WAITV(8);
    SBAR();
    // ph2: M1N1 ; stage b0.Ah0<-kt+2
    STAGE_A(0, 0, kt + 2);
    LOAD_A(0, 1);
    MMA(1, 1);
    SBAR();
    // ph3: M1N0 ; stage b0.Bh1<-kt+2 ; vmcnt(6)
    STAGE_B(0, 1, kt + 2);
    LOAD_B(0, 0);
    MMA(1, 0);
    WAITV(6);
    SBAR();
    // ph4: buf1 M0N0 ; stage b0.Bh0<-kt+2
    STAGE_B(0, 0, kt + 2);
    LOAD_A(1, 0); LOAD_B(1, 0);
    MMA(0, 0);
    SBAR();
    // ph5: M0N1 ; stage b0.Ah1<-kt+2 ; vmcnt(8)
    STAGE_A(0, 1, kt + 2);
    LOAD_B(1, 1);
    MMA(0, 1);
    WAITV(8);
    SBAR();
    // ph6: M1N1 ; stage b1.Ah0<-kt+3
    STAGE_A(1, 0, kt + 3);
    LOAD_A(1, 1);
    MMA(1, 1);
    SBAR();
    // ph7: M1N0 ; stage b1.Bh1<-kt+3 ; vmcnt(6)
    STAGE_B(1, 1, kt + 3);
    LOAD_B(1, 0);
    MMA(1, 0);
    WAITV(6);
    SBAR();
  }

  // epilogue: kt = 62 (buf0), 63 (buf1); stages only at e0/e1.
  STAGE_B(1, 0, KTILES - 1);
  LOAD_A(0, 0); LOAD_B(0, 0);
  MMA(0, 0);
  SBAR();
  STAGE_A(1, 1, KTILES - 1);
  LOAD_B(0, 1);
  MMA(0, 1);
  WAITV(8);
  SBAR();
  LOAD_A(0, 1);
  MMA(1, 1);
  SBAR();
  LOAD_B(0, 0);
  MMA(1, 0);
  WAITV(2);
  SBAR();
  LOAD_A(1, 0); LOAD_B(1, 0);
  MMA(0, 0);
  SBAR();
  LOAD_B(1, 1);
  MMA(0, 1);
  WAITV(0);
  SBAR();
  LOAD_A(1, 1);
  MMA(1, 1);
  SBAR();
  LOAD_B(1, 0);
  MMA(1, 0);

  // C write: D row = quad*4 + r, col = lane&15 within each 16x16 frag
#pragma unroll
  for (int i = 0; i < 8; i++) {
    const int mrow = (int)m0 + (i >> 2) * 128 + wm * 64 + (i & 3) * 16 + quad * 4;
#pragma unroll
    for (int j = 0; j < 4; j++) {
      const int ncol = (int)n0 + (j >> 1) * 128 + wn * 32 + (j & 1) * 16 + col;
      const float bv = bias[ncol];
      float* out = C + (size_t)mrow * N_OUT + ncol;
#pragma unroll
      for (int r = 0; r < 4; r++)
        __builtin_nontemporal_store(acc[i][j][r] + bv, out + (size_t)r * N_OUT);
    }
  }
}

// ---------------------------------------------------------------------------
// Fallback (ws too small): correct but slow fused kernel.
// ---------------------------------------------------------------------------
__global__ __launch_bounds__(256) void fallback_fused(const float* __restrict__ x,
                                                      const uint32_t* __restrict__ qw,
                                                      const uint32_t* __restrict__ qz,
                                                      const float* __restrict__ sc,
                                                      const float* __restrict__ bias,
                                                      float* __restrict__ out) {
  __shared__ float xs[K_IN];
  const int t = blockIdx.y;
  const int o = blockIdx.x * 256 + threadIdx.x;
  for (int i = threadIdx.x; i < K_IN; i += 256) xs[i] = x[(size_t)t * K_IN + i];
  __syncthreads();
  float acc = 0.f;
  const uint32_t* qwr = qw + (size_t)o * WPR;
  for (int g = 0; g < GROUPS; g++) {
    uint32_t zw = qz[o * (GROUPS / 8) + (g >> 3)];
    float zp = (float)((zw >> ((g & 7) * 4)) & 15u);
    float s = sc[o * GROUPS + g];
    float gacc = 0.f, gsum = 0.f;
    for (int w = 0; w < 8; w++) {
      uint32_t wv = qwr[g * 8 + w];
#pragma unroll
      for (int j = 0; j < 8; j++) {
        float xv = xs[g * 64 + w * 8 + j];
        gacc = fmaf((float)((wv >> (4 * j)) & 15u), xv, gacc);
        gsum += xv;
      }
    }
    acc += s * (gacc - zp * gsum);
  }
  out[(size_t)t * N_OUT + o] = acc + bias[o];
}

// ---------------------------------------------------------------------------
extern "C" void kernel_launch(void* const* d_in, const int* in_sizes, int n_in,
                              void* d_out, int out_size, void* d_ws, size_t ws_size,
                              hipStream_t stream) {
  (void)in_sizes; (void)n_in; (void)out_size;
  const float*    x    = (const float*)d_in[0];
  const uint32_t* qw   = (const uint32_t*)d_in[1];
  const uint32_t* qz   = (const uint32_t*)d_in[2];
  const float*    sc   = (const float*)d_in[3];
  const float*    bias = (const float*)d_in[4];
  float* out = (float*)d_out;

  const size_t xb_bytes = (size_t)M_TOK * K_IN * 2;
  const size_t wb_bytes = (size_t)N_OUT * K_IN * 2;

  if (ws_size >= xb_bytes + wb_bytes) {
    uint16_t* xb = (uint16_t*)d_ws;
    uint16_t* wb = (uint16_t*)((char*)d_ws + xb_bytes);
    prep<<<XBLK + WBLK, 256, 0, stream>>>(x, qw, qz, sc, xb, wb);
    gemm_bf16<<<NWG, 512, 0, stream>>>(xb, wb, bias, out);
  } else {
    fallback_fused<<<dim3(N_OUT / 256, M_TOK), 256, 0, stream>>>(x, qw, qz, sc, bias, out);
  }
}

// Round 7
// 574.615 us; speedup vs baseline: 1.0200x; 1.0164x over previous
//
#include <hip/hip_runtime.h>
#include <stdint.h>

#define M_TOK 4096
#define K_IN  4096
#define N_OUT 11008
#define GROUPS 64
#define WPR 512            // packed words per weight row = K_IN/8

// ---- 256x256 8-phase GEMM geometry ----
#define BM 256
#define BN 256
#define BK 64
#define TM (M_TOK / BM)    // 16
#define TN (N_OUT / BN)    // 43
#define NWG (TM * TN)      // 688  (688 % 8 == 0 -> simple bijective XCD swizzle)
#define KTILES (K_IN / BK) // 64

typedef __bf16 bf16x8 __attribute__((ext_vector_type(8)));
typedef float  f32x4  __attribute__((ext_vector_type(4)));

__device__ __forceinline__ uint16_t f2bf(float f) {
  uint32_t u = __float_as_uint(f);
  u += 0x7FFFu + ((u >> 16) & 1u);
  return (uint16_t)(u >> 16);
}

// ---------------------------------------------------------------------------
// Fused preprocessing (r5 form; measured equal across three variants).
// ---------------------------------------------------------------------------
#define XBLK ((M_TOK * K_IN) / (256 * 8))        // 8192
#define WBLK ((N_OUT * WPR) / (256 * 4))         // 5504

__global__ __launch_bounds__(256) void prep(const float* __restrict__ x,
                                            const uint32_t* __restrict__ qw,
                                            const uint32_t* __restrict__ qz,
                                            const float* __restrict__ sc,
                                            uint16_t* __restrict__ xb,
                                            uint16_t* __restrict__ wb) {
  if (blockIdx.x < XBLK) {
    size_t i = ((size_t)blockIdx.x * 256 + threadIdx.x) * 8;
    const float4* p = (const float4*)(x + i);
    float4 a = p[0];
    float4 b = p[1];
    uint4 v;
    v.x = (uint32_t)f2bf(a.x) | ((uint32_t)f2bf(a.y) << 16);
    v.y = (uint32_t)f2bf(a.z) | ((uint32_t)f2bf(a.w) << 16);
    v.z = (uint32_t)f2bf(b.x) | ((uint32_t)f2bf(b.y) << 16);
    v.w = (uint32_t)f2bf(b.z) | ((uint32_t)f2bf(b.w) << 16);
    *(uint4*)(xb + i) = v;
  } else {
    int t = (blockIdx.x - XBLK) * 256 + threadIdx.x;
    int o  = t >> 7;
    int g  = (t & 127) >> 1;
    uint32_t zw = qz[o * (GROUPS / 8) + (g >> 3)];
    float zp = (float)((zw >> ((g & 7) * 4)) & 15u);
    float s = sc[o * GROUPS + g];
    float c = -s * zp;
    uint4 w4 = ((const uint4*)qw)[t];
    uint4* out = (uint4*)wb + (size_t)t * 4;
    uint32_t ws[4] = {w4.x, w4.y, w4.z, w4.w};
#pragma unroll
    for (int q = 0; q < 4; q++) {
      uint32_t w = ws[q];
      uint4 v;
      uint32_t r[4];
#pragma unroll
      for (int j = 0; j < 4; j++) {
        float f0 = (float)((w >> (8 * j)) & 15u);
        float f1 = (float)((w >> (8 * j + 4)) & 15u);
        r[j] = (uint32_t)f2bf(fmaf(f0, s, c)) | ((uint32_t)f2bf(fmaf(f1, s, c)) << 16);
      }
      v.x = r[0]; v.y = r[1]; v.z = r[2]; v.w = r[3];
      out[q] = v;
    }
  }
}

// ---------------------------------------------------------------------------
// 256x256x64 GEMM, round 7: persistent B fragments (LDS-op reduction).
//
// r6 diagnosis: kernel is LDS-ISSUE-bound, not MFMA/barrier-bound.
//   ops/iter/CU = 448 ds_read_b128 + 128 LDS-writes = 576; measured 16.5
//   cyc/op. m201 (1563 TF) = 512 ops @ 12.9 cyc/op = its ds_read floor.
//   My 448 includes a Bh0 RE-read at ph3/ph7 (bfr overwritten at ph1/ph5).
// Fix: bfr[2][..] keeps BOTH B-halves live (+16 VGPR): Bh0 read once at
//   ph0 (ph4), consumed from registers at ph3 (ph7). Reads/wave/iter 56->48.
// Stage schedule, vmcnt ledger, swizzle, barrier placement: identical to r6.
//   Removed reads only ADD overwrite-ledger slack (b0.Bh0 last-read moves
//   ph3 -> ph0; its stage stays at ph4).
//   stages: ph0 b1.Bh0<-kt+1, ph1 b1.Ah1<-kt+1, ph2 b0.Ah0<-kt+2,
//           ph3 b0.Bh1<-kt+2, ph4 b0.Bh0<-kt+2, ph5 b0.Ah1<-kt+2,
//           ph6 b1.Ah0<-kt+3, ph7 b1.Bh1<-kt+3   (2 loads/thread each)
//   waits:  vmcnt(8)@ph1, vmcnt(6)@ph3, vmcnt(8)@ph5, vmcnt(6)@ph7
// ---------------------------------------------------------------------------
#define SBAR()   __builtin_amdgcn_s_barrier()
#define WAITV(n) asm volatile("s_waitcnt vmcnt(" #n ")" ::: "memory")

#define STAGE_A(buf, half, kt) do {                                            \
  _Pragma("unroll")                                                            \
  for (int c_ = 0; c_ < 2; c_++) {                                             \
    const int r_ = (half) * 128 + c_ * 64 + wave * 8;                          \
    __builtin_amdgcn_global_load_lds(                                          \
        (const __attribute__((address_space(1))) uint32_t*)(                   \
            gA + (size_t)r_ * K_IN + (size_t)(kt) * BK),                       \
        (__attribute__((address_space(3))) uint32_t*)(&As[(buf)][r_][0]),      \
        16, 0, 0);                                                             \
  } } while (0)

#define STAGE_B(buf, half, kt) do {                                            \
  _Pragma("unroll")                                                            \
  for (int c_ = 0; c_ < 2; c_++) {                                             \
    const int r_ = (half) * 128 + c_ * 64 + wave * 8;                          \
    __builtin_amdgcn_global_load_lds(                                          \
        (const __attribute__((address_space(1))) uint32_t*)(                   \
            gB + (size_t)r_ * K_IN + (size_t)(kt) * BK),                       \
        (__attribute__((address_space(3))) uint32_t*)(&Bs[(buf)][r_][0]),      \
        16, 0, 0);                                                             \
  } } while (0)

#define LOAD_A(buf, mh) do {                                                   \
  _Pragma("unroll")                                                            \
  for (int i2_ = 0; i2_ < 4; i2_++) {                                          \
    const int row_ = (mh) * 128 + wm * 64 + i2_ * 16 + col;                    \
    af[i2_][0] = *(const bf16x8*)&As[(buf)][row_][(quad ^ cs) << 3];           \
    af[i2_][1] = *(const bf16x8*)&As[(buf)][row_][((4 + quad) ^ cs) << 3];     \
  } } while (0)

// loads B-half (nh) into its PERSISTENT register set bfr[nh]
#define LOAD_B(buf, nh) do {                                                   \
  _Pragma("unroll")                                                            \
  for (int j2_ = 0; j2_ < 2; j2_++) {                                          \
    const int row_ = (nh) * 128 + wn * 32 + j2_ * 16 + col;                    \
    bfr[(nh)][j2_][0] = *(const bf16x8*)&Bs[(buf)][row_][(quad ^ cs) << 3];    \
    bfr[(nh)][j2_][1] = *(const bf16x8*)&Bs[(buf)][row_][((4 + quad) ^ cs) << 3]; \
  } } while (0)

#define MMA(mh, nh) do {                                                       \
  __builtin_amdgcn_s_setprio(1);                                               \
  _Pragma("unroll")                                                            \
  for (int i2_ = 0; i2_ < 4; i2_++)                                            \
    _Pragma("unroll")                                                          \
    for (int j2_ = 0; j2_ < 2; j2_++) {                                        \
      acc[(mh)*4 + i2_][(nh)*2 + j2_] = __builtin_amdgcn_mfma_f32_16x16x32_bf16( \
          af[i2_][0], bfr[(nh)][j2_][0], acc[(mh)*4 + i2_][(nh)*2 + j2_], 0, 0, 0); \
      acc[(mh)*4 + i2_][(nh)*2 + j2_] = __builtin_amdgcn_mfma_f32_16x16x32_bf16( \
          af[i2_][1], bfr[(nh)][j2_][1], acc[(mh)*4 + i2_][(nh)*2 + j2_], 0, 0, 0); \
    }                                                                          \
  __builtin_amdgcn_s_setprio(0); } while (0)

__global__ __launch_bounds__(512, 2) void gemm_bf16(const uint16_t* __restrict__ A,
                                                    const uint16_t* __restrict__ B,
                                                    const float* __restrict__ bias,
                                                    float* __restrict__ C) {
  __shared__ __align__(16) uint16_t As[2][BM][BK];   // 64 KiB
  __shared__ __align__(16) uint16_t Bs[2][BN][BK];   // 64 KiB

  const int bid = blockIdx.x;
  const int wg  = (bid & 7) * (NWG / 8) + (bid >> 3);
  const int mt  = wg / TN;
  const int nt  = wg % TN;
  const size_t m0 = (size_t)mt * BM;
  const size_t n0 = (size_t)nt * BN;

  const int tid  = threadIdx.x;
  const int wave = tid >> 6;
  const int lane = tid & 63;
  const int wm   = wave >> 2;          // 0..1
  const int wn   = wave & 3;           // 0..3
  const int lrow = lane >> 3;          // 0..7
  const int lcol = lane & 7;           // 0..7
  const int col  = lane & 15;
  const int quad = lane >> 4;
  const int cs   = col & 7;

  const uint16_t* gA = A + (m0 + lrow) * K_IN + (size_t)((lcol ^ lrow) << 3);
  const uint16_t* gB = B + (n0 + lrow) * K_IN + (size_t)((lcol ^ lrow) << 3);

  f32x4 acc[8][4];
#pragma unroll
  for (int i = 0; i < 8; i++)
#pragma unroll
    for (int j = 0; j < 4; j++)
      acc[i][j] = (f32x4){0.f, 0.f, 0.f, 0.f};

  bf16x8 af[4][2];        // A frags: one M-half (4 rows x 2 k-slices)
  bf16x8 bfr[2][2][2];    // B frags: BOTH N-halves persistent [nh][j][slice]

  // prologue: buf0 <- kt0, buf1.{Ah0,Bh1} <- kt1; keep 3 halves in flight.
  STAGE_A(0, 0, 0); STAGE_B(0, 1, 0); STAGE_B(0, 0, 0); STAGE_A(0, 1, 0);
  STAGE_A(1, 0, 1); STAGE_B(1, 1, 1);
  WAITV(6);
  SBAR();

  for (int it = 0; it < KTILES / 2 - 1; ++it) {
    const int kt = 2 * it;
    // ph0: buf0 M0N0 ; stage b1.Bh0<-kt+1
    STAGE_B(1, 0, kt + 1);
    LOAD_A(0, 0); LOAD_B(0, 0);
    MMA(0, 0);
    SBAR();
    // ph1: M0N1 ; stage b1.Ah1<-kt+1 ; vmcnt(8)
    STAGE_A(1, 1, kt + 1);
    LOAD_B(0, 1);
    MMA(0, 1);
    WAITV(8);
    SBAR();
    // ph2: M1N1 ; stage b0.Ah0<-kt+2   (reuses bfr[1])
    STAGE_A(0, 0, kt + 2);
    LOAD_A(0, 1);
    MMA(1, 1);
    SBAR();
    // ph3: M1N0 ; stage b0.Bh1<-kt+2 ; vmcnt(6)   (reuses bfr[0] - NO re-read)
    STAGE_B(0, 1, kt + 2);
    MMA(1, 0);
    WAITV(6);
    SBAR();
    // ph4: buf1 M0N0 ; stage b0.Bh0<-kt+2
    STAGE_B(0, 0, kt + 2);
    LOAD_A(1, 0); LOAD_B(1, 0);
    MMA(0, 0);
    SBAR();
    // ph5: M0N1 ; stage b0.Ah1<-kt+2 ; vmcnt(8)
    STAGE_A(0, 1, kt + 2);
    LOAD_B(1, 1);
    MMA(0, 1);
    WAITV(8);
    SBAR();
    // ph6: M1N1 ; stage b1.Ah0<-kt+3
    STAGE_A(1, 0, kt + 3);
    LOAD_A(1, 1);
    MMA(1, 1);
    SBAR();
    // ph7: M1N0 ; stage b1.Bh1<-kt+3 ; vmcnt(6)   (reuses bfr[0])
    STAGE_B(1, 1, kt + 3);
    MMA(1, 0);
    WAITV(6);
    SBAR();
  }

  // epilogue: kt = 62 (buf0), 63 (buf1); stages only at e0/e1.
  STAGE_B(1, 0, KTILES - 1);
  LOAD_A(0, 0); LOAD_B(0, 0);
  MMA(0, 0);
  SBAR();
  STAGE_A(1, 1, KTILES - 1);
  LOAD_B(0, 1);
  MMA(0, 1);
  WAITV(8);
  SBAR();
  LOAD_A(0, 1);
  MMA(1, 1);
  SBAR();
  MMA(1, 0);
  WAITV(2);
  SBAR();
  LOAD_A(1, 0); LOAD_B(1, 0);
  MMA(0, 0);
  SBAR();
  LOAD_B(1, 1);
  MMA(0, 1);
  WAITV(0);
  SBAR();
  LOAD_A(1, 1);
  MMA(1, 1);
  SBAR();
  MMA(1, 0);

  // C write: D row = quad*4 + r, col = lane&15 within each 16x16 frag
#pragma unroll
  for (int i = 0; i < 8; i++) {
    const int mrow = (int)m0 + (i >> 2) * 128 + wm * 64 + (i & 3) * 16 + quad * 4;
#pragma unroll
    for (int j = 0; j < 4; j++) {
      const int ncol = (int)n0 + (j >> 1) * 128 + wn * 32 + (j & 1) * 16 + col;
      const float bv = bias[ncol];
      float* out = C + (size_t)mrow * N_OUT + ncol;
#pragma unroll
      for (int r = 0; r < 4; r++)
        __builtin_nontemporal_store(acc[i][j][r] + bv, out + (size_t)r * N_OUT);
    }
  }
}

// ---------------------------------------------------------------------------
// Fallback (ws too small): correct but slow fused kernel.
// ---------------------------------------------------------------------------
__global__ __launch_bounds__(256) void fallback_fused(const float* __restrict__ x,
                                                      const uint32_t* __restrict__ qw,
                                                      const uint32_t* __restrict__ qz,
                                                      const float* __restrict__ sc,
                                                      const float* __restrict__ bias,
                                                      float* __restrict__ out) {
  __shared__ float xs[K_IN];
  const int t = blockIdx.y;
  const int o = blockIdx.x * 256 + threadIdx.x;
  for (int i = threadIdx.x; i < K_IN; i += 256) xs[i] = x[(size_t)t * K_IN + i];
  __syncthreads();
  float acc = 0.f;
  const uint32_t* qwr = qw + (size_t)o * WPR;
  for (int g = 0; g < GROUPS; g++) {
    uint32_t zw = qz[o * (GROUPS / 8) + (g >> 3)];
    float zp = (float)((zw >> ((g & 7) * 4)) & 15u);
    float s = sc[o * GROUPS + g];
    float gacc = 0.f, gsum = 0.f;
    for (int w = 0; w < 8; w++) {
      uint32_t wv = qwr[g * 8 + w];
#pragma unroll
      for (int j = 0; j < 8; j++) {
        float xv = xs[g * 64 + w * 8 + j];
        gacc = fmaf((float)((wv >> (4 * j)) & 15u), xv, gacc);
        gsum += xv;
      }
    }
    acc += s * (gacc - zp * gsum);
  }
  out[(size_t)t * N_OUT + o] = acc + bias[o];
}

// ---------------------------------------------------------------------------
extern "C" void kernel_launch(void* const* d_in, const int* in_sizes, int n_in,
                              void* d_out, int out_size, void* d_ws, size_t ws_size,
                              hipStream_t stream) {
  (void)in_sizes; (void)n_in; (void)out_size;
  const float*    x    = (const float*)d_in[0];
  const uint32_t* qw   = (const uint32_t*)d_in[1];
  const uint32_t* qz   = (const uint32_t*)d_in[2];
  const float*    sc   = (const float*)d_in[3];
  const float*    bias = (const float*)d_in[4];
  float* out = (float*)d_out;

  const size_t xb_bytes = (size_t)M_TOK * K_IN * 2;
  const size_t wb_bytes = (size_t)N_OUT * K_IN * 2;

  if (ws_size >= xb_bytes + wb_bytes) {
    uint16_t* xb = (uint16_t*)d_ws;
    uint16_t* wb = (uint16_t*)((char*)d_ws + xb_bytes);
    prep<<<XBLK + WBLK, 256, 0, stream>>>(x, qw, qz, sc, xb, wb);
    gemm_bf16<<<NWG, 512, 0, stream>>>(xb, wb, bias, out);
  } else {
    fallback_fused<<<dim3(N_OUT / 256, M_TOK), 256, 0, stream>>>(x, qw, qz, sc, bias, out);
  }
}